// Round 11
// baseline (711.478 us; speedup 1.0000x reference)
//
#include <hip/hip_runtime.h>

#define N_NODES 100000
#define N_EDGES 500000
#define NODE_IN 16
#define HID 128
#define LPAD 140          // LDS row stride (floats): float4-aligned, breaks pow-2 striding
#define SCAN_CHUNK 1024
#define NB_SCAN ((N_NODES + SCAN_CHUNK - 1) / SCAN_CHUNK)   // 98

typedef __attribute__((ext_vector_type(8))) short short8;   // 8 bf16 in 4 VGPRs
typedef __attribute__((ext_vector_type(4))) float f32x4;    // MFMA accumulator

__device__ __forceinline__ float elu_f(float v) {
    return v > 0.f ? v : __expf(v) - 1.f;
}

// bf16 pack/unpack (rne)
__device__ __forceinline__ unsigned short f2b(float f) {
    unsigned int u = __float_as_uint(f);
    unsigned int r = (u + 0x7fffu + ((u >> 16) & 1u)) >> 16;
    return (unsigned short)r;
}
__device__ __forceinline__ float b2f(unsigned short h) {
    return __uint_as_float((unsigned int)h << 16);
}

// ===========================================================================
// CSR-by-dst build: deg -> rowPtr (3-phase scan) -> cursor -> payload reorder
// ===========================================================================
__global__ void deg_count_kernel(const int* __restrict__ ei, int* __restrict__ deg) {
    int e = blockIdx.x * 256 + threadIdx.x;
    if (e < N_EDGES) atomicAdd(&deg[ei[N_EDGES + e]], 1);
}

__global__ __launch_bounds__(1024) void scanA_kernel(const int* __restrict__ deg, int* __restrict__ bsum) {
    __shared__ int s[SCAN_CHUNK];
    int i = blockIdx.x * SCAN_CHUNK + threadIdx.x;
    s[threadIdx.x] = (i < N_NODES) ? deg[i] : 0;
    __syncthreads();
    for (int off = SCAN_CHUNK / 2; off > 0; off >>= 1) {
        if (threadIdx.x < off) s[threadIdx.x] += s[threadIdx.x + off];
        __syncthreads();
    }
    if (threadIdx.x == 0) bsum[blockIdx.x] = s[0];
}

__global__ void scanB_kernel(const int* __restrict__ bsum, int* __restrict__ boff,
                             int* __restrict__ rowPtr) {
    if (threadIdx.x == 0 && blockIdx.x == 0) {
        int r = 0;
        for (int i = 0; i < NB_SCAN; i++) { boff[i] = r; r += bsum[i]; }
        rowPtr[N_NODES] = N_EDGES;     // sentinel
    }
}

__global__ __launch_bounds__(1024) void scanC_kernel(const int* __restrict__ deg,
                                                     const int* __restrict__ boff,
                                                     int* __restrict__ rowPtr,
                                                     int* __restrict__ cursor) {
    __shared__ int bufA[SCAN_CHUNK], bufB[SCAN_CHUNK];
    int i = blockIdx.x * SCAN_CHUNK + threadIdx.x;
    int t = threadIdx.x;
    bufA[t] = (i < N_NODES) ? deg[i] : 0;
    __syncthreads();
    int* src = bufA; int* dst = bufB;
    for (int off = 1; off < SCAN_CHUNK; off <<= 1) {
        dst[t] = (t >= off) ? (src[t - off] + src[t]) : src[t];
        __syncthreads();
        int* tmp = src; src = dst; dst = tmp;
    }
    if (i < N_NODES) {
        int excl = (t == 0) ? 0 : src[t - 1];
        int v = excl + boff[blockIdx.x];
        rowPtr[i] = v;
        cursor[i] = v;
    }
}

// payload reorder: (src, ea) packed int2 in CSR(dst) order — one 8B load/edge
__global__ void fill_kernel(const int* __restrict__ ei, const float* __restrict__ ea,
                            int* __restrict__ cursor, int2* __restrict__ edgeP) {
    int e = blockIdx.x * 256 + threadIdx.x;
    if (e < N_EDGES) {
        int d = ei[N_EDGES + e];
        int p = atomicAdd(&cursor[d], 1);
        edgeP[p] = make_int2(ei[e], __float_as_int(ea[e]));
    }
}

// ===========================================================================
// Weight pack: W [ (K_off..K_off+127) x 128 ] row-major -> MFMA B-fragment
// order, split hi/lo bf16. B-frag (16x16x32): lane holds B[k][n] with
// n = lane&15, k = chunk*32 + (lane>>4)*8 + j.  idx = ((ch*8+tl)*64+lane)*8+j
// ===========================================================================
__global__ __launch_bounds__(256) void pack_w_kernel(const float* __restrict__ W, int K_off,
                                                     unsigned short* __restrict__ hi,
                                                     unsigned short* __restrict__ lo)
{
    int gid = blockIdx.x * 256 + threadIdx.x;      // 2048 per matrix
    if (gid >= 4 * 8 * 64) return;
    int lane = gid & 63, tl = (gid >> 6) & 7, ch = gid >> 9;
    int kb = ch * 32 + (lane >> 4) * 8;
    int n  = tl * 16 + (lane & 15);
    for (int j = 0; j < 8; j++) {
        float w = W[(size_t)(K_off + kb + j) * 128 + n];
        unsigned short h = f2b(w);
        hi[(size_t)gid * 8 + j] = h;
        lo[(size_t)gid * 8 + j] = f2b(w - b2f(h));
    }
}

// ===========================================================================
// Layer 0 scatter (NODE_IN=16, cheap: 8M atomics)
// ===========================================================================
__global__ __launch_bounds__(256) void scatter0_kernel(
    const float* __restrict__ x, const int* __restrict__ ei,
    const float* __restrict__ ea, const float* __restrict__ We0,
    const float* __restrict__ be0, float* __restrict__ aggr)
{
    int idx = blockIdx.x * 256 + threadIdx.x;
    int e = idx >> 4, c = idx & 15;
    int s = ei[e], d = ei[N_EDGES + e];
    float m = x[s * NODE_IN + c] + ea[e] * We0[c] + be0[c];
    m = fmaxf(m, 0.f);
    atomicAdd(&aggr[d * NODE_IN + c], m);
}

// ---------------------------------------------------------------------------
__device__ __forceinline__ void fma4x4(float (&acc)[4][4],
    const float4& r0, const float4& r1, const float4& r2, const float4& r3,
    const float4& w0, const float4& w1, const float4& w2, const float4& w3)
{
    float r[4][4] = {{r0.x, r0.y, r0.z, r0.w}, {r1.x, r1.y, r1.z, r1.w},
                     {r2.x, r2.y, r2.z, r2.w}, {r3.x, r3.y, r3.z, r3.w}};
    float w[4][4] = {{w0.x, w0.y, w0.z, w0.w}, {w1.x, w1.y, w1.z, w1.w},
                     {w2.x, w2.y, w2.z, w2.w}, {w3.x, w3.y, w3.z, w3.w}};
#pragma unroll
    for (int i = 0; i < 4; i++)
#pragma unroll
        for (int k = 0; k < 4; k++)
#pragma unroll
            for (int c = 0; c < 4; c++)
                acc[i][c] = fmaf(r[i][k], w[k][c], acc[i][c]);
}

// ===========================================================================
// Layer 0 MLP (fp32 vector — small, left as-is)
// ===========================================================================
__global__ __launch_bounds__(256) void mlp0_kernel(
    const float* __restrict__ x, const float* __restrict__ aggr,
    const float* __restrict__ W1, const float* __restrict__ b1,
    const float* __restrict__ W2, const float* __restrict__ b2,
    float* __restrict__ h)
{
    __shared__ float in0[32][20];
    __shared__ float mid[32][HID];
    const int t = threadIdx.x;
    const int q = t & 31, g = t >> 5;
    const int c0 = q * 4;
    const int base = blockIdx.x * 32;

    for (int i = t; i < 32 * NODE_IN; i += 256) {
        int r = i >> 4, cc = i & 15;
        int n = base + r;
        in0[r][cc] = x[n * NODE_IN + cc] + aggr[n * NODE_IN + cc];
    }
    __syncthreads();

    float4 bb = *(const float4*)&b1[c0];
    float acc[4][4];
#pragma unroll
    for (int i = 0; i < 4; i++) { acc[i][0] = bb.x; acc[i][1] = bb.y; acc[i][2] = bb.z; acc[i][3] = bb.w; }
    for (int k = 0; k < NODE_IN; k += 4) {
        float4 r0 = *(const float4*)&in0[g * 4 + 0][k];
        float4 r1 = *(const float4*)&in0[g * 4 + 1][k];
        float4 r2 = *(const float4*)&in0[g * 4 + 2][k];
        float4 r3 = *(const float4*)&in0[g * 4 + 3][k];
        float4 w0 = *(const float4*)&W1[(k + 0) * HID + c0];
        float4 w1 = *(const float4*)&W1[(k + 1) * HID + c0];
        float4 w2 = *(const float4*)&W1[(k + 2) * HID + c0];
        float4 w3 = *(const float4*)&W1[(k + 3) * HID + c0];
        fma4x4(acc, r0, r1, r2, r3, w0, w1, w2, w3);
    }
#pragma unroll
    for (int i = 0; i < 4; i++)
        *(float4*)&mid[g * 4 + i][c0] = make_float4(elu_f(acc[i][0]), elu_f(acc[i][1]),
                                                    elu_f(acc[i][2]), elu_f(acc[i][3]));
    __syncthreads();

    float4 bb2 = *(const float4*)&b2[c0];
    float acc2[4][4];
#pragma unroll
    for (int i = 0; i < 4; i++) { acc2[i][0] = bb2.x; acc2[i][1] = bb2.y; acc2[i][2] = bb2.z; acc2[i][3] = bb2.w; }
    for (int k = 0; k < HID; k += 4) {
        float4 r0 = *(const float4*)&mid[g * 4 + 0][k];
        float4 r1 = *(const float4*)&mid[g * 4 + 1][k];
        float4 r2 = *(const float4*)&mid[g * 4 + 2][k];
        float4 r3 = *(const float4*)&mid[g * 4 + 3][k];
        float4 w0 = *(const float4*)&W2[(k + 0) * HID + c0];
        float4 w1 = *(const float4*)&W2[(k + 1) * HID + c0];
        float4 w2 = *(const float4*)&W2[(k + 2) * HID + c0];
        float4 w3 = *(const float4*)&W2[(k + 3) * HID + c0];
        fma4x4(acc2, r0, r1, r2, r3, w0, w1, w2, w3);
    }
#pragma unroll
    for (int i = 0; i < 4; i++)
        *(float4*)&h[(base + g * 4 + i) * HID + c0] = make_float4(
            elu_f(acc2[i][0]), elu_f(acc2[i][1]), elu_f(acc2[i][2]), elu_f(acc2[i][3]));
}

// ---------------------------------------------------------------------------
// A-fragment load+split from LDS: lane holds A[m][k], m=lane&15,
// k = ch*32 + (lane>>4)*8 + j  [HW-verified mapping, learn_hip m120]
// All reads complete into registers BEFORE any caller LDS write -> in-place ok
// ---------------------------------------------------------------------------
__device__ __forceinline__ void afrag_split(const float (&buf)[16][LPAD], int lane,
                                            short8 (&ah)[4], short8 (&al)[4])
{
    const int m = lane & 15, s8 = (lane >> 4) * 8;
#pragma unroll
    for (int ch = 0; ch < 4; ch++) {
        float4 a0 = *(const float4*)&buf[m][ch * 32 + s8];
        float4 a1 = *(const float4*)&buf[m][ch * 32 + s8 + 4];
        float av[8] = {a0.x, a0.y, a0.z, a0.w, a1.x, a1.y, a1.z, a1.w};
#pragma unroll
        for (int j = 0; j < 8; j++) {
            unsigned short h = f2b(av[j]);
            ah[ch][j] = (short)h;
            al[ch][j] = (short)f2b(av[j] - b2f(h));
        }
    }
}

// ===========================================================================
// Fused GINE HID layer, v9: fp32 pipelined gather + split-bf16 MFMA MLP,
// SINGLE LDS buffer (8.96 KB -> 18-block/CU LDS cap; in-place is safe for
// 1-wave blocks: A-frags fully register-resident before writes).
// 1 wave / block, 16 nodes / block, grid 6250.
// ===========================================================================
template <bool PRED>
__global__ __launch_bounds__(64) void gine_mfma_kernel(
    const float* __restrict__ hin, const int* __restrict__ rowPtr,
    const int2* __restrict__ edgeP,
    const float* __restrict__ We, const float* __restrict__ be,
    const unsigned short* __restrict__ W1h, const unsigned short* __restrict__ W1l,
    const float* __restrict__ b1,
    const unsigned short* __restrict__ W2h, const unsigned short* __restrict__ W2l,
    const float* __restrict__ b2,
    float* __restrict__ hout,
    const unsigned short* __restrict__ P1h, const unsigned short* __restrict__ P1l,
    const unsigned short* __restrict__ P2h, const unsigned short* __restrict__ P2l,
    unsigned short* __restrict__ Pbuf)
{
    __shared__ float buf[16][LPAD];    // 8.96 KB, single buffer (in-place MLP)
    const int lane = threadIdx.x;
    const int qg = lane & 15, rg = lane >> 4;
    const int c0 = qg * 8;             // gather: 16 lanes x 8 cols
    const int base = blockIdx.x * 16;

    // ---- stage 1: pipelined gather (8 slots = 2 steps x 4 rows in flight) ----
    float4 wev0 = *(const float4*)&We[c0];
    float4 wev1 = *(const float4*)&We[c0 + 4];
    float4 bev0 = *(const float4*)&be[c0];
    float4 bev1 = *(const float4*)&be[c0 + 4];

    int s0[4], e0[4];
    float4 acca[4], accb[4];
#pragma unroll
    for (int i = 0; i < 4; i++) {
        int n = base + rg * 4 + i;
        s0[i] = rowPtr[n];
        e0[i] = rowPtr[n + 1];
        acca[i] = *(const float4*)&hin[(size_t)n * HID + c0];
        accb[i] = *(const float4*)&hin[(size_t)n * HID + c0 + 4];
    }
    int maxd = 0;
#pragma unroll
    for (int i = 0; i < 4; i++) maxd = max(maxd, e0[i] - s0[i]);

    int idx[8]; float av[8]; bool act[8];
#pragma unroll
    for (int u = 0; u < 2; u++)
#pragma unroll
        for (int i = 0; i < 4; i++) {
            int slot = u * 4 + i;
            int j = s0[i] + u;
            act[slot] = j < e0[i];
            int jc = act[slot] ? j : (N_EDGES - 1);
            int2 ep = edgeP[jc];
            idx[slot] = ep.x;
            av[slot]  = __int_as_float(ep.y);
        }

    for (int sb = 0; sb < maxd; sb += 2) {
        float4 hva[8], hvb[8];
#pragma unroll
        for (int s = 0; s < 8; s++) {
            const float* p = &hin[(size_t)idx[s] * HID + c0];
            hva[s] = *(const float4*)p;
            hvb[s] = *(const float4*)(p + 4);
        }
        int nidx[8]; float nav[8]; bool nact[8];
#pragma unroll
        for (int u = 0; u < 2; u++)
#pragma unroll
            for (int i = 0; i < 4; i++) {
                int slot = u * 4 + i;
                int j = s0[i] + sb + 2 + u;
                nact[slot] = j < e0[i];
                int jc = nact[slot] ? j : (N_EDGES - 1);
                int2 ep = edgeP[jc];
                nidx[slot] = ep.x;
                nav[slot]  = __int_as_float(ep.y);
            }
#pragma unroll
        for (int u = 0; u < 2; u++)
#pragma unroll
            for (int i = 0; i < 4; i++) {
                int slot = u * 4 + i;
                if (act[slot]) {
                    acca[i].x += fmaxf(fmaf(av[slot], wev0.x, bev0.x) + hva[slot].x, 0.f);
                    acca[i].y += fmaxf(fmaf(av[slot], wev0.y, bev0.y) + hva[slot].y, 0.f);
                    acca[i].z += fmaxf(fmaf(av[slot], wev0.z, bev0.z) + hva[slot].z, 0.f);
                    acca[i].w += fmaxf(fmaf(av[slot], wev0.w, bev0.w) + hva[slot].w, 0.f);
                    accb[i].x += fmaxf(fmaf(av[slot], wev1.x, bev1.x) + hvb[slot].x, 0.f);
                    accb[i].y += fmaxf(fmaf(av[slot], wev1.y, bev1.y) + hvb[slot].y, 0.f);
                    accb[i].z += fmaxf(fmaf(av[slot], wev1.z, bev1.z) + hvb[slot].z, 0.f);
                    accb[i].w += fmaxf(fmaf(av[slot], wev1.w, bev1.w) + hvb[slot].w, 0.f);
                }
            }
#pragma unroll
        for (int s = 0; s < 8; s++) {
            idx[s] = nidx[s]; av[s] = nav[s]; act[s] = nact[s];
        }
    }
#pragma unroll
    for (int i = 0; i < 4; i++) {
        *(float4*)&buf[rg * 4 + i][c0]     = acca[i];
        *(float4*)&buf[rg * 4 + i][c0 + 4] = accb[i];
    }
    __syncthreads();

    const int col16 = lane & 15, r0 = (lane >> 4) * 4;

    // ---- stage 2: mid = elu(in @ W1 + b1), split-bf16 MFMA, in-place ----
    {
        short8 ah[4], al[4];
        afrag_split(buf, lane, ah, al);       // fully in registers before writes
        float res[8][4];
#pragma unroll
        for (int tl = 0; tl < 8; tl++) {
            int col = tl * 16 + col16;
            float bv = b1[col];
            f32x4 c = {bv, bv, bv, bv};
#pragma unroll
            for (int ch = 0; ch < 4; ch++) {
                int off = ((ch * 8 + tl) * 64 + lane) * 8;
                short8 bh = *(const short8*)&W1h[off];
                short8 bl = *(const short8*)&W1l[off];
                c = __builtin_amdgcn_mfma_f32_16x16x32_bf16(ah[ch], bh, c, 0, 0, 0);
                c = __builtin_amdgcn_mfma_f32_16x16x32_bf16(al[ch], bh, c, 0, 0, 0);
                c = __builtin_amdgcn_mfma_f32_16x16x32_bf16(ah[ch], bl, c, 0, 0, 0);
            }
#pragma unroll
            for (int r = 0; r < 4; r++) res[tl][r] = elu_f(c[r]);
        }
        __syncthreads();
#pragma unroll
        for (int tl = 0; tl < 8; tl++)
#pragma unroll
            for (int r = 0; r < 4; r++)
                buf[r0 + r][tl * 16 + col16] = res[tl][r];
    }
    __syncthreads();

    // ---- stage 3: h = elu(mid @ W2 + b2), in-place ----
    {
        short8 ah[4], al[4];
        afrag_split(buf, lane, ah, al);
        float res[8][4];
#pragma unroll
        for (int tl = 0; tl < 8; tl++) {
            int col = tl * 16 + col16;
            float bv = b2[col];
            f32x4 c = {bv, bv, bv, bv};
#pragma unroll
            for (int ch = 0; ch < 4; ch++) {
                int off = ((ch * 8 + tl) * 64 + lane) * 8;
                short8 bh = *(const short8*)&W2h[off];
                short8 bl = *(const short8*)&W2l[off];
                c = __builtin_amdgcn_mfma_f32_16x16x32_bf16(ah[ch], bh, c, 0, 0, 0);
                c = __builtin_amdgcn_mfma_f32_16x16x32_bf16(al[ch], bh, c, 0, 0, 0);
                c = __builtin_amdgcn_mfma_f32_16x16x32_bf16(ah[ch], bl, c, 0, 0, 0);
            }
#pragma unroll
            for (int r = 0; r < 4; r++) res[tl][r] = elu_f(c[r]);
        }
        __syncthreads();
#pragma unroll
        for (int tl = 0; tl < 8; tl++)
#pragma unroll
            for (int r = 0; r < 4; r++)
                buf[r0 + r][tl * 16 + col16] = res[tl][r];
    }
    __syncthreads();

    if constexpr (!PRED) {
        // coalesced store of h from buf
#pragma unroll
        for (int i = 0; i < 4; i++) {
            int n = base + rg * 4 + i;
            *(float4*)&hout[(size_t)n * HID + c0]     = *(const float4*)&buf[rg * 4 + i][c0];
            *(float4*)&hout[(size_t)n * HID + c0 + 4] = *(const float4*)&buf[rg * 4 + i][c0 + 4];
        }
    } else {
        // P1|P2 = h @ Wp1 halves, emit bf16 packed rows
        short8 ah[4], al[4];
        afrag_split(buf, lane, ah, al);
#pragma unroll
        for (int tl = 0; tl < 8; tl++) {
            int col = tl * 16 + col16;
            f32x4 c1 = {0.f, 0.f, 0.f, 0.f};
            f32x4 c2 = {0.f, 0.f, 0.f, 0.f};
#pragma unroll
            for (int ch = 0; ch < 4; ch++) {
                int off = ((ch * 8 + tl) * 64 + lane) * 8;
                short8 bh1 = *(const short8*)&P1h[off];
                short8 bl1 = *(const short8*)&P1l[off];
                c1 = __builtin_amdgcn_mfma_f32_16x16x32_bf16(ah[ch], bh1, c1, 0, 0, 0);
                c1 = __builtin_amdgcn_mfma_f32_16x16x32_bf16(al[ch], bh1, c1, 0, 0, 0);
                c1 = __builtin_amdgcn_mfma_f32_16x16x32_bf16(ah[ch], bl1, c1, 0, 0, 0);
                short8 bh2 = *(const short8*)&P2h[off];
                short8 bl2 = *(const short8*)&P2l[off];
                c2 = __builtin_amdgcn_mfma_f32_16x16x32_bf16(ah[ch], bh2, c2, 0, 0, 0);
                c2 = __builtin_amdgcn_mfma_f32_16x16x32_bf16(al[ch], bh2, c2, 0, 0, 0);
                c2 = __builtin_amdgcn_mfma_f32_16x16x32_bf16(ah[ch], bl2, c2, 0, 0, 0);
            }
#pragma unroll
            for (int r = 0; r < 4; r++) {
                size_t n = base + r0 + r;
                Pbuf[n * 256 + col]       = f2b(c1[r]);
                Pbuf[n * 256 + 128 + col] = f2b(c2[r]);
            }
        }
    }
}

// ===========================================================================
// Edge predictor tail: out[e] = elu(P1[src]+P2[dst]+bp1) . Wp2 + bp2
// ===========================================================================
__global__ __launch_bounds__(256) void pred_edge_kernel(
    const unsigned short* __restrict__ Pbuf, const int* __restrict__ ei,
    const float* __restrict__ bp1, const float* __restrict__ Wp2,
    const float* __restrict__ bp2, float* __restrict__ out)
{
    const int t = threadIdx.x;
    const int lane = t & 31;
    const int eloc = t >> 5;
    const int e = blockIdx.x * 8 + eloc;
    const int c0 = lane * 4;

    int s = ei[e], d = ei[N_EDGES + e];
    ushort4 ua = *(const ushort4*)&Pbuf[s * 256 + c0];
    ushort4 ub = *(const ushort4*)&Pbuf[d * 256 + 128 + c0];
    float4 bb = *(const float4*)&bp1[c0];
    float4 w = *(const float4*)&Wp2[c0];
    float r = elu_f(b2f(ua.x) + b2f(ub.x) + bb.x) * w.x
            + elu_f(b2f(ua.y) + b2f(ub.y) + bb.y) * w.y
            + elu_f(b2f(ua.z) + b2f(ub.z) + bb.z) * w.z
            + elu_f(b2f(ua.w) + b2f(ub.w) + bb.w) * w.w;
#pragma unroll
    for (int off = 16; off > 0; off >>= 1) r += __shfl_down(r, off, 32);
    if (lane == 0) out[e] = r + bp2[0];
}

// ===========================================================================
extern "C" void kernel_launch(void* const* d_in, const int* in_sizes, int n_in,
                              void* d_out, int out_size, void* d_ws, size_t ws_size,
                              hipStream_t stream) {
    const float* x    = (const float*)d_in[0];
    const int*   ei   = (const int*)d_in[1];
    const float* ea   = (const float*)d_in[2];
    const float* We0  = (const float*)d_in[3];
    const float* be0  = (const float*)d_in[4];
    const float* W10  = (const float*)d_in[5];
    const float* b10  = (const float*)d_in[6];
    const float* W20  = (const float*)d_in[7];
    const float* b20  = (const float*)d_in[8];
    const float* We_s = (const float*)d_in[9];
    const float* be_s = (const float*)d_in[10];
    const float* W1_s = (const float*)d_in[11];
    const float* b1_s = (const float*)d_in[12];
    const float* W2_s = (const float*)d_in[13];
    const float* b2_s = (const float*)d_in[14];
    const float* Wp1  = (const float*)d_in[15];
    const float* bp1  = (const float*)d_in[16];
    const float* Wp2  = (const float*)d_in[17];
    const float* bp2  = (const float*)d_in[18];
    float* out = (float*)d_out;

    // workspace: hA | hB | R   (R = aggr0+CSR low, packed weights at +32MB)
    float* hA = (float*)d_ws;                          // 12.8M f32
    float* hB = hA + (size_t)N_NODES * HID;            // 12.8M f32
    float* R  = hB + (size_t)N_NODES * HID;            // 12.8M f32 region

    float* aggr0 = R;                                  // N*16 f32
    int* deg     = (int*)(aggr0 + (size_t)N_NODES * NODE_IN);
    int* rowPtr  = deg + N_NODES;                      // N+1 ints
    int* cursor  = rowPtr + N_NODES + 1;
    int2* edgeP  = (int2*)(cursor + N_NODES);          // 500k int2 (4 MB)
    int* bsum    = (int*)(edgeP + N_EDGES);
    int* boff    = bsum + NB_SCAN;

    // packed weights: 20 slots x 16384 ushorts (32 KB) = 640 KB, at R+32MB
    unsigned short* wpk = (unsigned short*)(R + (size_t)8 * 1024 * 1024);
    const size_t WSLOT = 16384;

    // ----- CSR build -----
    hipMemsetAsync(deg, 0, N_NODES * sizeof(int), stream);
    deg_count_kernel<<<(N_EDGES + 255) / 256, 256, 0, stream>>>(ei, deg);
    scanA_kernel<<<NB_SCAN, SCAN_CHUNK, 0, stream>>>(deg, bsum);
    scanB_kernel<<<1, 64, 0, stream>>>(bsum, boff, rowPtr);
    scanC_kernel<<<NB_SCAN, SCAN_CHUNK, 0, stream>>>(deg, boff, rowPtr, cursor);
    fill_kernel<<<(N_EDGES + 255) / 256, 256, 0, stream>>>(ei, ea, cursor, edgeP);

    // ----- weight packing -----
    for (int l = 0; l < 4; l++) {
        pack_w_kernel<<<8, 256, 0, stream>>>(W1_s + (size_t)l * 16384, 0,
                                             wpk + (0 + l) * WSLOT, wpk + (4 + l) * WSLOT);
        pack_w_kernel<<<8, 256, 0, stream>>>(W2_s + (size_t)l * 16384, 0,
                                             wpk + (8 + l) * WSLOT, wpk + (12 + l) * WSLOT);
    }
    pack_w_kernel<<<8, 256, 0, stream>>>(Wp1, 0,   wpk + 16 * WSLOT, wpk + 17 * WSLOT);
    pack_w_kernel<<<8, 256, 0, stream>>>(Wp1, 128, wpk + 18 * WSLOT, wpk + 19 * WSLOT);

    // ----- layer 0 (NODE_IN -> HID) -----
    hipMemsetAsync(aggr0, 0, (size_t)N_NODES * NODE_IN * sizeof(float), stream);
    scatter0_kernel<<<(N_EDGES * NODE_IN) / 256, 256, 0, stream>>>(x, ei, ea, We0, be0, aggr0);
    mlp0_kernel<<<N_NODES / 32, 256, 0, stream>>>(x, aggr0, W10, b10, W20, b20, hA);

    // ----- layers 1..3 (HID -> HID), ping-pong: A->B->A->B -----
    float* hin = hA; float* hout_ = hB;
    for (int l = 0; l < 3; l++) {
        gine_mfma_kernel<false><<<N_NODES / 16, 64, 0, stream>>>(
            hin, rowPtr, edgeP,
            We_s + l * HID, be_s + l * HID,
            wpk + (0 + l) * WSLOT, wpk + (4 + l) * WSLOT, b1_s + l * HID,
            wpk + (8 + l) * WSLOT, wpk + (12 + l) * WSLOT, b2_s + l * HID,
            hout_, nullptr, nullptr, nullptr, nullptr, nullptr);
        float* tmp = hin; hin = hout_; hout_ = tmp;
    }
    // hin == hB; hA free -> bf16 P1|P2 (51.2 MB)

    // ----- layer 4 fused with pred GEMM -----
    unsigned short* Pbuf = (unsigned short*)hA;
    {
        const int l = 3;
        gine_mfma_kernel<true><<<N_NODES / 16, 64, 0, stream>>>(
            hin, rowPtr, edgeP,
            We_s + l * HID, be_s + l * HID,
            wpk + (0 + l) * WSLOT, wpk + (4 + l) * WSLOT, b1_s + l * HID,
            wpk + (8 + l) * WSLOT, wpk + (12 + l) * WSLOT, b2_s + l * HID,
            nullptr, wpk + 16 * WSLOT, wpk + 17 * WSLOT,
            wpk + 18 * WSLOT, wpk + 19 * WSLOT, Pbuf);
    }

    // ----- edge predictor tail -----
    pred_edge_kernel<<<N_EDGES / 8, 256, 0, stream>>>(Pbuf, ei, bp1, Wp2, bp2, out);
}

// Round 12
// 616.807 us; speedup vs baseline: 1.1535x; 1.1535x over previous
//
#include <hip/hip_runtime.h>

#define N_NODES 100000
#define N_EDGES 500000
#define NODE_IN 16
#define HID 128
#define LPAD 140          // LDS row stride (floats)
#define SCAN_CHUNK 1024
#define NB_SCAN ((N_NODES + SCAN_CHUNK - 1) / SCAN_CHUNK)   // 98

typedef __attribute__((ext_vector_type(8))) short short8;   // 8×16b in 4 VGPRs
typedef __attribute__((ext_vector_type(4))) float f32x4;    // MFMA accumulator

__device__ __forceinline__ float elu_f(float v) {
    return v > 0.f ? v : __expf(v) - 1.f;
}

// bf16 pack/unpack (rne)
__device__ __forceinline__ unsigned short f2b(float f) {
    unsigned int u = __float_as_uint(f);
    unsigned int r = (u + 0x7fffu + ((u >> 16) & 1u)) >> 16;
    return (unsigned short)r;
}
__device__ __forceinline__ float b2f(unsigned short h) {
    return __uint_as_float((unsigned int)h << 16);
}
// fp16 pack/unpack (rne via v_cvt)
__device__ __forceinline__ unsigned short f2h(float f) {
    _Float16 h = (_Float16)f;
    unsigned short u;
    __builtin_memcpy(&u, &h, 2);
    return u;
}
__device__ __forceinline__ float h2f(unsigned short u) {
    _Float16 h;
    __builtin_memcpy(&h, &u, 2);
    return (float)h;
}

// ===========================================================================
// CSR-by-dst build
// ===========================================================================
__global__ void deg_count_kernel(const int* __restrict__ ei, int* __restrict__ deg) {
    int e = blockIdx.x * 256 + threadIdx.x;
    if (e < N_EDGES) atomicAdd(&deg[ei[N_EDGES + e]], 1);
}

__global__ __launch_bounds__(1024) void scanA_kernel(const int* __restrict__ deg, int* __restrict__ bsum) {
    __shared__ int s[SCAN_CHUNK];
    int i = blockIdx.x * SCAN_CHUNK + threadIdx.x;
    s[threadIdx.x] = (i < N_NODES) ? deg[i] : 0;
    __syncthreads();
    for (int off = SCAN_CHUNK / 2; off > 0; off >>= 1) {
        if (threadIdx.x < off) s[threadIdx.x] += s[threadIdx.x + off];
        __syncthreads();
    }
    if (threadIdx.x == 0) bsum[blockIdx.x] = s[0];
}

__global__ void scanB_kernel(const int* __restrict__ bsum, int* __restrict__ boff,
                             int* __restrict__ rowPtr) {
    if (threadIdx.x == 0 && blockIdx.x == 0) {
        int r = 0;
        for (int i = 0; i < NB_SCAN; i++) { boff[i] = r; r += bsum[i]; }
        rowPtr[N_NODES] = N_EDGES;
    }
}

__global__ __launch_bounds__(1024) void scanC_kernel(const int* __restrict__ deg,
                                                     const int* __restrict__ boff,
                                                     int* __restrict__ rowPtr,
                                                     int* __restrict__ cursor) {
    __shared__ int bufA[SCAN_CHUNK], bufB[SCAN_CHUNK];
    int i = blockIdx.x * SCAN_CHUNK + threadIdx.x;
    int t = threadIdx.x;
    bufA[t] = (i < N_NODES) ? deg[i] : 0;
    __syncthreads();
    int* src = bufA; int* dst = bufB;
    for (int off = 1; off < SCAN_CHUNK; off <<= 1) {
        dst[t] = (t >= off) ? (src[t - off] + src[t]) : src[t];
        __syncthreads();
        int* tmp = src; src = dst; dst = tmp;
    }
    if (i < N_NODES) {
        int excl = (t == 0) ? 0 : src[t - 1];
        int v = excl + boff[blockIdx.x];
        rowPtr[i] = v;
        cursor[i] = v;
    }
}

// payload reorder: (src, ea) packed int2 in CSR(dst) order
__global__ void fill_kernel(const int* __restrict__ ei, const float* __restrict__ ea,
                            int* __restrict__ cursor, int2* __restrict__ edgeP) {
    int e = blockIdx.x * 256 + threadIdx.x;
    if (e < N_EDGES) {
        int d = ei[N_EDGES + e];
        int p = atomicAdd(&cursor[d], 1);
        edgeP[p] = make_int2(ei[e], __float_as_int(ea[e]));
    }
}

// ===========================================================================
// Weight pack -> MFMA B-fragment order, split hi/lo bf16
// ===========================================================================
__global__ __launch_bounds__(256) void pack_w_kernel(const float* __restrict__ W, int K_off,
                                                     unsigned short* __restrict__ hi,
                                                     unsigned short* __restrict__ lo)
{
    int gid = blockIdx.x * 256 + threadIdx.x;      // 2048 per matrix
    if (gid >= 4 * 8 * 64) return;
    int lane = gid & 63, tl = (gid >> 6) & 7, ch = gid >> 9;
    int kb = ch * 32 + (lane >> 4) * 8;
    int n  = tl * 16 + (lane & 15);
    for (int j = 0; j < 8; j++) {
        float w = W[(size_t)(K_off + kb + j) * 128 + n];
        unsigned short h = f2b(w);
        hi[(size_t)gid * 8 + j] = h;
        lo[(size_t)gid * 8 + j] = f2b(w - b2f(h));
    }
}

// ===========================================================================
// Layer 0 scatter (fp32 aggr, NODE_IN=16)
// ===========================================================================
__global__ __launch_bounds__(256) void scatter0_kernel(
    const float* __restrict__ x, const int* __restrict__ ei,
    const float* __restrict__ ea, const float* __restrict__ We0,
    const float* __restrict__ be0, float* __restrict__ aggr)
{
    int idx = blockIdx.x * 256 + threadIdx.x;
    int e = idx >> 4, c = idx & 15;
    int s = ei[e], d = ei[N_EDGES + e];
    float m = x[s * NODE_IN + c] + ea[e] * We0[c] + be0[c];
    m = fmaxf(m, 0.f);
    atomicAdd(&aggr[d * NODE_IN + c], m);
}

// ---------------------------------------------------------------------------
__device__ __forceinline__ void fma4x4(float (&acc)[4][4],
    const float4& r0, const float4& r1, const float4& r2, const float4& r3,
    const float4& w0, const float4& w1, const float4& w2, const float4& w3)
{
    float r[4][4] = {{r0.x, r0.y, r0.z, r0.w}, {r1.x, r1.y, r1.z, r1.w},
                     {r2.x, r2.y, r2.z, r2.w}, {r3.x, r3.y, r3.z, r3.w}};
    float w[4][4] = {{w0.x, w0.y, w0.z, w0.w}, {w1.x, w1.y, w1.z, w1.w},
                     {w2.x, w2.y, w2.z, w2.w}, {w3.x, w3.y, w3.z, w3.w}};
#pragma unroll
    for (int i = 0; i < 4; i++)
#pragma unroll
        for (int k = 0; k < 4; k++)
#pragma unroll
            for (int c = 0; c < 4; c++)
                acc[i][c] = fmaf(r[i][k], w[k][c], acc[i][c]);
}

// ===========================================================================
// Layer 0 MLP (fp32 vector) -> writes h as fp16
// ===========================================================================
__global__ __launch_bounds__(256) void mlp0_kernel(
    const float* __restrict__ x, const float* __restrict__ aggr,
    const float* __restrict__ W1, const float* __restrict__ b1,
    const float* __restrict__ W2, const float* __restrict__ b2,
    unsigned short* __restrict__ h)
{
    __shared__ float in0[32][20];
    __shared__ float mid[32][HID];
    const int t = threadIdx.x;
    const int q = t & 31, g = t >> 5;
    const int c0 = q * 4;
    const int base = blockIdx.x * 32;

    for (int i = t; i < 32 * NODE_IN; i += 256) {
        int r = i >> 4, cc = i & 15;
        int n = base + r;
        in0[r][cc] = x[n * NODE_IN + cc] + aggr[n * NODE_IN + cc];
    }
    __syncthreads();

    float4 bb = *(const float4*)&b1[c0];
    float acc[4][4];
#pragma unroll
    for (int i = 0; i < 4; i++) { acc[i][0] = bb.x; acc[i][1] = bb.y; acc[i][2] = bb.z; acc[i][3] = bb.w; }
    for (int k = 0; k < NODE_IN; k += 4) {
        float4 r0 = *(const float4*)&in0[g * 4 + 0][k];
        float4 r1 = *(const float4*)&in0[g * 4 + 1][k];
        float4 r2 = *(const float4*)&in0[g * 4 + 2][k];
        float4 r3 = *(const float4*)&in0[g * 4 + 3][k];
        float4 w0 = *(const float4*)&W1[(k + 0) * HID + c0];
        float4 w1 = *(const float4*)&W1[(k + 1) * HID + c0];
        float4 w2 = *(const float4*)&W1[(k + 2) * HID + c0];
        float4 w3 = *(const float4*)&W1[(k + 3) * HID + c0];
        fma4x4(acc, r0, r1, r2, r3, w0, w1, w2, w3);
    }
#pragma unroll
    for (int i = 0; i < 4; i++)
        *(float4*)&mid[g * 4 + i][c0] = make_float4(elu_f(acc[i][0]), elu_f(acc[i][1]),
                                                    elu_f(acc[i][2]), elu_f(acc[i][3]));
    __syncthreads();

    float4 bb2 = *(const float4*)&b2[c0];
    float acc2[4][4];
#pragma unroll
    for (int i = 0; i < 4; i++) { acc2[i][0] = bb2.x; acc2[i][1] = bb2.y; acc2[i][2] = bb2.z; acc2[i][3] = bb2.w; }
    for (int k = 0; k < HID; k += 4) {
        float4 r0 = *(const float4*)&mid[g * 4 + 0][k];
        float4 r1 = *(const float4*)&mid[g * 4 + 1][k];
        float4 r2 = *(const float4*)&mid[g * 4 + 2][k];
        float4 r3 = *(const float4*)&mid[g * 4 + 3][k];
        float4 w0 = *(const float4*)&W2[(k + 0) * HID + c0];
        float4 w1 = *(const float4*)&W2[(k + 1) * HID + c0];
        float4 w2 = *(const float4*)&W2[(k + 2) * HID + c0];
        float4 w3 = *(const float4*)&W2[(k + 3) * HID + c0];
        fma4x4(acc2, r0, r1, r2, r3, w0, w1, w2, w3);
    }
#pragma unroll
    for (int i = 0; i < 4; i++) {
        ushort4 o;
        o.x = f2h(elu_f(acc2[i][0])); o.y = f2h(elu_f(acc2[i][1]));
        o.z = f2h(elu_f(acc2[i][2])); o.w = f2h(elu_f(acc2[i][3]));
        *(ushort4*)&h[(size_t)(base + g * 4 + i) * HID + c0] = o;
    }
}

// ---------------------------------------------------------------------------
// A-fragment load+split from LDS (fp32 -> hi/lo bf16), layout per m120
// ---------------------------------------------------------------------------
__device__ __forceinline__ void afrag_split(const float (&buf)[16][LPAD], int lane,
                                            short8 (&ah)[4], short8 (&al)[4])
{
    const int m = lane & 15, s8 = (lane >> 4) * 8;
#pragma unroll
    for (int ch = 0; ch < 4; ch++) {
        float4 a0 = *(const float4*)&buf[m][ch * 32 + s8];
        float4 a1 = *(const float4*)&buf[m][ch * 32 + s8 + 4];
        float av[8] = {a0.x, a0.y, a0.z, a0.w, a1.x, a1.y, a1.z, a1.w};
#pragma unroll
        for (int j = 0; j < 8; j++) {
            unsigned short h = f2b(av[j]);
            ah[ch][j] = (short)h;
            al[ch][j] = (short)f2b(av[j] - b2f(h));
        }
    }
}

// ===========================================================================
// Fused GINE HID layer, v10: fp16 h storage (256 B rows -> one 16 B load per
// lane per edge-slot), fp32 accumulate, split-bf16 MFMA MLP, single 8.96 KB
// LDS buffer, 1 wave / 16 nodes / block.
// ===========================================================================
template <bool PRED>
__global__ __launch_bounds__(64) void gine_mfma_kernel(
    const unsigned short* __restrict__ hin, const int* __restrict__ rowPtr,
    const int2* __restrict__ edgeP,
    const float* __restrict__ We, const float* __restrict__ be,
    const unsigned short* __restrict__ W1h, const unsigned short* __restrict__ W1l,
    const float* __restrict__ b1,
    const unsigned short* __restrict__ W2h, const unsigned short* __restrict__ W2l,
    const float* __restrict__ b2,
    unsigned short* __restrict__ hout,
    const unsigned short* __restrict__ P1h, const unsigned short* __restrict__ P1l,
    const unsigned short* __restrict__ P2h, const unsigned short* __restrict__ P2l,
    unsigned short* __restrict__ Pbuf)
{
    __shared__ float buf[16][LPAD];    // 8.96 KB, single buffer
    const int lane = threadIdx.x;
    const int qg = lane & 15, rg = lane >> 4;
    const int c0 = qg * 8;             // 16 lanes x 8 cols
    const int base = blockIdx.x * 16;

    float wev[8], bev[8];
#pragma unroll
    for (int j = 0; j < 8; j++) { wev[j] = We[c0 + j]; bev[j] = be[c0 + j]; }

    // ---- stage 1: pipelined gather (8 slots, one 16B fp16 load per slot) ----
    int s0[4], e0[4];
    float acc[4][8];
#pragma unroll
    for (int i = 0; i < 4; i++) {
        int n = base + rg * 4 + i;
        s0[i] = rowPtr[n];
        e0[i] = rowPtr[n + 1];
        short8 h0 = *(const short8*)&hin[(size_t)n * HID + c0];
#pragma unroll
        for (int j = 0; j < 8; j++) acc[i][j] = h2f((unsigned short)h0[j]);
    }
    int maxd = 0;
#pragma unroll
    for (int i = 0; i < 4; i++) maxd = max(maxd, e0[i] - s0[i]);

    int idx[8]; float av[8]; bool act[8];
#pragma unroll
    for (int u = 0; u < 2; u++)
#pragma unroll
        for (int i = 0; i < 4; i++) {
            int slot = u * 4 + i;
            int j = s0[i] + u;
            act[slot] = j < e0[i];
            int jc = act[slot] ? j : (N_EDGES - 1);
            int2 ep = edgeP[jc];
            idx[slot] = ep.x;
            av[slot]  = __int_as_float(ep.y);
        }

    for (int sb = 0; sb < maxd; sb += 2) {
        short8 hraw[8];
#pragma unroll
        for (int s = 0; s < 8; s++)
            hraw[s] = *(const short8*)&hin[(size_t)idx[s] * HID + c0];

        int nidx[8]; float nav[8]; bool nact[8];
#pragma unroll
        for (int u = 0; u < 2; u++)
#pragma unroll
            for (int i = 0; i < 4; i++) {
                int slot = u * 4 + i;
                int j = s0[i] + sb + 2 + u;
                nact[slot] = j < e0[i];
                int jc = nact[slot] ? j : (N_EDGES - 1);
                int2 ep = edgeP[jc];
                nidx[slot] = ep.x;
                nav[slot]  = __int_as_float(ep.y);
            }

#pragma unroll
        for (int u = 0; u < 2; u++)
#pragma unroll
            for (int i = 0; i < 4; i++) {
                int slot = u * 4 + i;
                if (act[slot]) {
#pragma unroll
                    for (int j = 0; j < 8; j++) {
                        float hv = h2f((unsigned short)hraw[slot][j]);
                        acc[i][j] += fmaxf(fmaf(av[slot], wev[j], bev[j]) + hv, 0.f);
                    }
                }
            }
#pragma unroll
        for (int s = 0; s < 8; s++) {
            idx[s] = nidx[s]; av[s] = nav[s]; act[s] = nact[s];
        }
    }
#pragma unroll
    for (int i = 0; i < 4; i++) {
        *(float4*)&buf[rg * 4 + i][c0]     = make_float4(acc[i][0], acc[i][1], acc[i][2], acc[i][3]);
        *(float4*)&buf[rg * 4 + i][c0 + 4] = make_float4(acc[i][4], acc[i][5], acc[i][6], acc[i][7]);
    }
    __syncthreads();

    const int col16 = lane & 15, r0 = (lane >> 4) * 4;

    // ---- stage 2: mid = elu(in @ W1 + b1), split-bf16 MFMA, in-place ----
    {
        short8 ah[4], al[4];
        afrag_split(buf, lane, ah, al);
        float res[8][4];
#pragma unroll
        for (int tl = 0; tl < 8; tl++) {
            int col = tl * 16 + col16;
            float bv = b1[col];
            f32x4 c = {bv, bv, bv, bv};
#pragma unroll
            for (int ch = 0; ch < 4; ch++) {
                int off = ((ch * 8 + tl) * 64 + lane) * 8;
                short8 bh = *(const short8*)&W1h[off];
                short8 bl = *(const short8*)&W1l[off];
                c = __builtin_amdgcn_mfma_f32_16x16x32_bf16(ah[ch], bh, c, 0, 0, 0);
                c = __builtin_amdgcn_mfma_f32_16x16x32_bf16(al[ch], bh, c, 0, 0, 0);
                c = __builtin_amdgcn_mfma_f32_16x16x32_bf16(ah[ch], bl, c, 0, 0, 0);
            }
#pragma unroll
            for (int r = 0; r < 4; r++) res[tl][r] = elu_f(c[r]);
        }
        __syncthreads();
#pragma unroll
        for (int tl = 0; tl < 8; tl++)
#pragma unroll
            for (int r = 0; r < 4; r++)
                buf[r0 + r][tl * 16 + col16] = res[tl][r];
    }
    __syncthreads();

    // ---- stage 3: h = elu(mid @ W2 + b2), in-place ----
    {
        short8 ah[4], al[4];
        afrag_split(buf, lane, ah, al);
        float res[8][4];
#pragma unroll
        for (int tl = 0; tl < 8; tl++) {
            int col = tl * 16 + col16;
            float bv = b2[col];
            f32x4 c = {bv, bv, bv, bv};
#pragma unroll
            for (int ch = 0; ch < 4; ch++) {
                int off = ((ch * 8 + tl) * 64 + lane) * 8;
                short8 bh = *(const short8*)&W2h[off];
                short8 bl = *(const short8*)&W2l[off];
                c = __builtin_amdgcn_mfma_f32_16x16x32_bf16(ah[ch], bh, c, 0, 0, 0);
                c = __builtin_amdgcn_mfma_f32_16x16x32_bf16(al[ch], bh, c, 0, 0, 0);
                c = __builtin_amdgcn_mfma_f32_16x16x32_bf16(ah[ch], bl, c, 0, 0, 0);
            }
#pragma unroll
            for (int r = 0; r < 4; r++) res[tl][r] = elu_f(c[r]);
        }
        __syncthreads();
#pragma unroll
        for (int tl = 0; tl < 8; tl++)
#pragma unroll
            for (int r = 0; r < 4; r++)
                buf[r0 + r][tl * 16 + col16] = res[tl][r];
    }
    __syncthreads();

    if constexpr (!PRED) {
        // fp16 store of h from buf (16 B per lane per row)
#pragma unroll
        for (int i = 0; i < 4; i++) {
            int n = base + rg * 4 + i;
            short8 o;
#pragma unroll
            for (int j = 0; j < 8; j++) o[j] = (short)f2h(buf[rg * 4 + i][c0 + j]);
            *(short8*)&hout[(size_t)n * HID + c0] = o;
        }
    } else {
        // P1|P2 = h @ Wp1 halves, emit bf16 packed rows
        short8 ah[4], al[4];
        afrag_split(buf, lane, ah, al);
#pragma unroll
        for (int tl = 0; tl < 8; tl++) {
            int col = tl * 16 + col16;
            f32x4 c1 = {0.f, 0.f, 0.f, 0.f};
            f32x4 c2 = {0.f, 0.f, 0.f, 0.f};
#pragma unroll
            for (int ch = 0; ch < 4; ch++) {
                int off = ((ch * 8 + tl) * 64 + lane) * 8;
                short8 bh1 = *(const short8*)&P1h[off];
                short8 bl1 = *(const short8*)&P1l[off];
                c1 = __builtin_amdgcn_mfma_f32_16x16x32_bf16(ah[ch], bh1, c1, 0, 0, 0);
                c1 = __builtin_amdgcn_mfma_f32_16x16x32_bf16(al[ch], bh1, c1, 0, 0, 0);
                c1 = __builtin_amdgcn_mfma_f32_16x16x32_bf16(ah[ch], bl1, c1, 0, 0, 0);
                short8 bh2 = *(const short8*)&P2h[off];
                short8 bl2 = *(const short8*)&P2l[off];
                c2 = __builtin_amdgcn_mfma_f32_16x16x32_bf16(ah[ch], bh2, c2, 0, 0, 0);
                c2 = __builtin_amdgcn_mfma_f32_16x16x32_bf16(al[ch], bh2, c2, 0, 0, 0);
                c2 = __builtin_amdgcn_mfma_f32_16x16x32_bf16(ah[ch], bl2, c2, 0, 0, 0);
            }
#pragma unroll
            for (int r = 0; r < 4; r++) {
                size_t n = base + r0 + r;
                Pbuf[n * 256 + col]       = f2b(c1[r]);
                Pbuf[n * 256 + 128 + col] = f2b(c2[r]);
            }
        }
    }
}

// ===========================================================================
// Edge predictor tail
// ===========================================================================
__global__ __launch_bounds__(256) void pred_edge_kernel(
    const unsigned short* __restrict__ Pbuf, const int* __restrict__ ei,
    const float* __restrict__ bp1, const float* __restrict__ Wp2,
    const float* __restrict__ bp2, float* __restrict__ out)
{
    const int t = threadIdx.x;
    const int lane = t & 31;
    const int eloc = t >> 5;
    const int e = blockIdx.x * 8 + eloc;
    const int c0 = lane * 4;

    int s = ei[e], d = ei[N_EDGES + e];
    ushort4 ua = *(const ushort4*)&Pbuf[(size_t)s * 256 + c0];
    ushort4 ub = *(const ushort4*)&Pbuf[(size_t)d * 256 + 128 + c0];
    float4 bb = *(const float4*)&bp1[c0];
    float4 w = *(const float4*)&Wp2[c0];
    float r = elu_f(b2f(ua.x) + b2f(ub.x) + bb.x) * w.x
            + elu_f(b2f(ua.y) + b2f(ub.y) + bb.y) * w.y
            + elu_f(b2f(ua.z) + b2f(ub.z) + bb.z) * w.z
            + elu_f(b2f(ua.w) + b2f(ub.w) + bb.w) * w.w;
#pragma unroll
    for (int off = 16; off > 0; off >>= 1) r += __shfl_down(r, off, 32);
    if (lane == 0) out[e] = r + bp2[0];
}

// ===========================================================================
extern "C" void kernel_launch(void* const* d_in, const int* in_sizes, int n_in,
                              void* d_out, int out_size, void* d_ws, size_t ws_size,
                              hipStream_t stream) {
    const float* x    = (const float*)d_in[0];
    const int*   ei   = (const int*)d_in[1];
    const float* ea   = (const float*)d_in[2];
    const float* We0  = (const float*)d_in[3];
    const float* be0  = (const float*)d_in[4];
    const float* W10  = (const float*)d_in[5];
    const float* b10  = (const float*)d_in[6];
    const float* W20  = (const float*)d_in[7];
    const float* b20  = (const float*)d_in[8];
    const float* We_s = (const float*)d_in[9];
    const float* be_s = (const float*)d_in[10];
    const float* W1_s = (const float*)d_in[11];
    const float* b1_s = (const float*)d_in[12];
    const float* W2_s = (const float*)d_in[13];
    const float* b2_s = (const float*)d_in[14];
    const float* Wp1  = (const float*)d_in[15];
    const float* bp1  = (const float*)d_in[16];
    const float* Wp2  = (const float*)d_in[17];
    const float* bp2  = (const float*)d_in[18];
    float* out = (float*)d_out;

    // workspace: h16A (25.6MB) | h16B (25.6MB) | Pbuf (51.2MB) | R
    unsigned short* h16A = (unsigned short*)d_ws;
    unsigned short* h16B = h16A + (size_t)N_NODES * HID;
    unsigned short* Pbuf = h16B + (size_t)N_NODES * HID;
    float* R = (float*)(Pbuf + (size_t)N_NODES * 256);

    float* aggr0 = R;                                  // N*16 f32
    int* deg     = (int*)(aggr0 + (size_t)N_NODES * NODE_IN);
    int* rowPtr  = deg + N_NODES;                      // N+1 ints
    int* cursor  = rowPtr + N_NODES + 1;
    int2* edgeP  = (int2*)(cursor + N_NODES);          // 500k int2
    int* bsum    = (int*)(edgeP + N_EDGES);
    int* boff    = bsum + NB_SCAN;

    // packed weights: 20 slots x 16384 ushorts = 640 KB, after boff (aligned up)
    unsigned short* wpk = (unsigned short*)(R + (size_t)6 * 1024 * 1024);  // +24MB into R
    const size_t WSLOT = 16384;

    // ----- CSR build -----
    hipMemsetAsync(deg, 0, N_NODES * sizeof(int), stream);
    deg_count_kernel<<<(N_EDGES + 255) / 256, 256, 0, stream>>>(ei, deg);
    scanA_kernel<<<NB_SCAN, SCAN_CHUNK, 0, stream>>>(deg, bsum);
    scanB_kernel<<<1, 64, 0, stream>>>(bsum, boff, rowPtr);
    scanC_kernel<<<NB_SCAN, SCAN_CHUNK, 0, stream>>>(deg, boff, rowPtr, cursor);
    fill_kernel<<<(N_EDGES + 255) / 256, 256, 0, stream>>>(ei, ea, cursor, edgeP);

    // ----- weight packing -----
    for (int l = 0; l < 4; l++) {
        pack_w_kernel<<<8, 256, 0, stream>>>(W1_s + (size_t)l * 16384, 0,
                                             wpk + (0 + l) * WSLOT, wpk + (4 + l) * WSLOT);
        pack_w_kernel<<<8, 256, 0, stream>>>(W2_s + (size_t)l * 16384, 0,
                                             wpk + (8 + l) * WSLOT, wpk + (12 + l) * WSLOT);
    }
    pack_w_kernel<<<8, 256, 0, stream>>>(Wp1, 0,   wpk + 16 * WSLOT, wpk + 17 * WSLOT);
    pack_w_kernel<<<8, 256, 0, stream>>>(Wp1, 128, wpk + 18 * WSLOT, wpk + 19 * WSLOT);

    // ----- layer 0 (NODE_IN -> HID) -----
    hipMemsetAsync(aggr0, 0, (size_t)N_NODES * NODE_IN * sizeof(float), stream);
    scatter0_kernel<<<(N_EDGES * NODE_IN) / 256, 256, 0, stream>>>(x, ei, ea, We0, be0, aggr0);
    mlp0_kernel<<<N_NODES / 32, 256, 0, stream>>>(x, aggr0, W10, b10, W20, b20, h16A);

    // ----- layers 1..3 (HID -> HID), ping-pong -----
    unsigned short* hin = h16A; unsigned short* hout_ = h16B;
    for (int l = 0; l < 3; l++) {
        gine_mfma_kernel<false><<<N_NODES / 16, 64, 0, stream>>>(
            hin, rowPtr, edgeP,
            We_s + l * HID, be_s + l * HID,
            wpk + (0 + l) * WSLOT, wpk + (4 + l) * WSLOT, b1_s + l * HID,
            wpk + (8 + l) * WSLOT, wpk + (12 + l) * WSLOT, b2_s + l * HID,
            hout_, nullptr, nullptr, nullptr, nullptr, nullptr);
        unsigned short* tmp = hin; hin = hout_; hout_ = tmp;
    }
    // hin == h16B after 3 swaps

    // ----- layer 4 fused with pred GEMM -----
    {
        const int l = 3;
        gine_mfma_kernel<true><<<N_NODES / 16, 64, 0, stream>>>(
            hin, rowPtr, edgeP,
            We_s + l * HID, be_s + l * HID,
            wpk + (0 + l) * WSLOT, wpk + (4 + l) * WSLOT, b1_s + l * HID,
            wpk + (8 + l) * WSLOT, wpk + (12 + l) * WSLOT, b2_s + l * HID,
            nullptr, wpk + 16 * WSLOT, wpk + 17 * WSLOT,
            wpk + 18 * WSLOT, wpk + 19 * WSLOT, Pbuf);
    }

    // ----- edge predictor tail -----
    pred_edge_kernel<<<N_EDGES / 8, 256, 0, stream>>>(Pbuf, ei, bp1, Wp2, bp2, out);
}